// Round 4
// baseline (52696.027 us; speedup 1.0000x reference)
//
#include <hip/hip_runtime.h>
#include <math.h>

#define N_PTS 32768
#define M_SEL 8192
#define K_NBR 64
#define F_IN  64
#define H_MID 128
#define C_OUT 128
#define NCELL 512   // 8x8x8 grid
#define CAP   192   // per-centroid candidate cap

// ---------- helpers ----------

__device__ __forceinline__ int clamp8(int v) { return v < 0 ? 0 : (v > 7 ? 7 : v); }

__device__ __forceinline__ int cell_of(float px, float py, float pz) {
    int ix = clamp8((int)(px * 8.0f));
    int iy = clamp8((int)(py * 8.0f));
    int iz = clamp8((int)(pz * 8.0f));
    return (iz * 8 + iy) * 8 + ix;
}

// Bit-exact replica of numpy: ((dx*dx + dy*dy) + dz*dz), rn, no fma.
__device__ __forceinline__ float d2_exact(float ax, float ay, float az,
                                          float bx, float by, float bz) {
#pragma clang fp contract(off)
    float dx = ax - bx, dy = ay - by, dz = az - bz;
    return (dx * dx + dy * dy) + dz * dz;
}

// ---------- binning ----------

__global__ void bin_count_kernel(const float* __restrict__ pos, int* __restrict__ cnt) {
    int i = blockIdx.x * blockDim.x + threadIdx.x;
    if (i < N_PTS) {
        atomicAdd(&cnt[cell_of(pos[3*i], pos[3*i+1], pos[3*i+2])], 1);
    }
}

__global__ void scan_kernel(const int* __restrict__ cnt, int* __restrict__ start,
                            int* __restrict__ fill) {
    __shared__ int s[NCELL];
    int t = threadIdx.x;
    int v = cnt[t];
    s[t] = v;
    __syncthreads();
    for (int off = 1; off < NCELL; off <<= 1) {
        int add = (t >= off) ? s[t - off] : 0;
        __syncthreads();
        s[t] += add;
        __syncthreads();
    }
    int ex = s[t] - v;           // exclusive scan
    start[t] = ex;
    fill[t]  = ex;
    if (t == NCELL - 1) start[NCELL] = s[t];
}

// pq[slot] = (x, y, z, orig_index_as_float_bits) — one dwordx4 per point
__global__ void scatter_kernel(const float* __restrict__ pos, int* __restrict__ fill,
                               float4* __restrict__ pq) {
    int i = blockIdx.x * blockDim.x + threadIdx.x;
    if (i < N_PTS) {
        float px = pos[3*i], py = pos[3*i+1], pz = pos[3*i+2];
        int c = cell_of(px, py, pz);
        int slot = atomicAdd(&fill[c], 1);
        pq[slot] = make_float4(px, py, pz, __int_as_float(i));
    }
}

// ---------- FPS ----------
// Single workgroup. Per-cell state = packed u64 (float_bits(max mind) << 32 | ~orig)
// in LDS, updated with ds_max_u64 atomics (no per-cell butterflies). mind[] is
// LDS-resident. Flagged-cell -> wave assignment is round-robin, computed
// replicated in every wave via ballots. 2 barriers/iteration.

__global__ __launch_bounds__(1024) void fps_kernel(
        const float4* __restrict__ pq, const int* __restrict__ cstart,
        const float* __restrict__ pos, int* __restrict__ sel) {
    __shared__ float s_mind[N_PTS];                     // 128 KB
    __shared__ unsigned long long s_pack[NCELL];        // 4 KB
    __shared__ int s_cs[NCELL + 1];

    const int tid  = threadIdx.x;
    const int lane = tid & 63;
    const int wid  = tid >> 6;
    const unsigned long long lmask_lt = (1ULL << lane) - 1ULL;

    for (int i = tid; i < N_PTS; i += 1024) s_mind[i] = INFINITY;
    for (int i = tid; i < NCELL + 1; i += 1024) s_cs[i] = cstart[i];
    if (tid < NCELL) {
        // +inf sentinel => every nonempty cell flagged on iteration 1; empty = 0
        s_pack[tid] = (cstart[tid + 1] > cstart[tid])
                      ? ((0x7F800000ULL << 32) | 0xFFFFFFFFULL) : 0ULL;
    }
    if (tid == 0) sel[0] = 0;
    // p held in registers, uniform across all threads (reduce is replicated)
    float px = pos[0], py = pos[1], pz = pos[2];
    __syncthreads();

    // ---- initial flags + round-robin assignment (replicated per wave) ----
    unsigned long long ab[8];
    {
        unsigned int cum = 0;
        #pragma unroll
        for (int k = 0; k < 8; ++k) {
            const int c = lane + (k << 6);
            const float cm = __uint_as_float((unsigned int)(s_pack[c] >> 32));
            const float lox = (float)(c & 7)        * 0.125f;
            const float loy = (float)((c >> 3) & 7) * 0.125f;
            const float loz = (float)(c >> 6)       * 0.125f;
            float dx = fmaxf(fmaxf(lox - px, px - (lox + 0.125f)), 0.0f);
            float dy = fmaxf(fmaxf(loy - py, py - (loy + 0.125f)), 0.0f);
            float dz = fmaxf(fmaxf(loz - pz, pz - (loz + 0.125f)), 0.0f);
            float lb2 = dx * dx + dy * dy + dz * dz;
            bool fl = (lb2 * 0.999f < cm);              // conservative
            unsigned long long b = __ballot(fl);
            unsigned int rank = cum + (unsigned int)__popcll(b & lmask_lt);
            ab[k] = __ballot(fl && ((rank & 15u) == (unsigned)wid));
            cum += (unsigned int)__popcll(b);
        }
    }

    for (int m = 1; m < M_SEL; ++m) {
        __syncthreads();          // prior flag/reduce reads vs this B's writes

        // ---- B: update assigned cells (reset slot + atomicMax per point) ----
        #pragma unroll
        for (int k = 0; k < 8; ++k) {
            unsigned long long mask = ab[k];
            while (mask) {
                const int bit = __ffsll((long long)mask) - 1;
                mask &= mask - 1;
                const int c = bit + (k << 6);
                if (lane == 0) s_pack[c] = 0ULL;        // in-order before atomics
                const int cs = s_cs[c], ce = s_cs[c + 1];
                for (int j = cs + lane; j < ce; j += 64) {
                    const float4 q  = pq[j];
                    const float d2  = d2_exact(q.x, q.y, q.z, px, py, pz);
                    const float old = s_mind[j];
                    const float nv  = d2 < old ? d2 : old;
                    if (nv < old) s_mind[j] = nv;
                    const unsigned long long pk =
                        ((unsigned long long)__float_as_uint(nv) << 32)
                        | (unsigned long long)(~(unsigned int)__float_as_int(q.w));
                    atomicMax(&s_pack[c], pk);
                }
            }
        }
        __syncthreads();

        // ---- C: replicated global argmax over 512 cells ----
        unsigned long long vk[8];
        unsigned long long best = 0ULL;
        #pragma unroll
        for (int k = 0; k < 8; ++k) {
            vk[k] = s_pack[lane + (k << 6)];
            if (vk[k] > best) best = vk[k];
        }
        #pragma unroll
        for (int off = 1; off < 64; off <<= 1) {
            unsigned long long o = __shfl_xor(best, off);
            if (o > best) best = o;
        }
        const unsigned int orig = ~(unsigned int)best;
        if (tid == 0) sel[m] = (int)orig;
        px = pos[3 * orig]; py = pos[3 * orig + 1]; pz = pos[3 * orig + 2];

        // ---- flags + assignment for next iteration (uses vk regs) ----
        unsigned int cum = 0;
        #pragma unroll
        for (int k = 0; k < 8; ++k) {
            const int c = lane + (k << 6);
            const float cm = __uint_as_float((unsigned int)(vk[k] >> 32));
            const float lox = (float)(c & 7)        * 0.125f;
            const float loy = (float)((c >> 3) & 7) * 0.125f;
            const float loz = (float)(c >> 6)       * 0.125f;
            float dx = fmaxf(fmaxf(lox - px, px - (lox + 0.125f)), 0.0f);
            float dy = fmaxf(fmaxf(loy - py, py - (loy + 0.125f)), 0.0f);
            float dz = fmaxf(fmaxf(loz - pz, pz - (loz + 0.125f)), 0.0f);
            float lb2 = dx * dx + dy * dy + dz * dz;
            bool fl = (lb2 * 0.999f < cm);
            unsigned long long b = __ballot(fl);
            unsigned int rank = cum + (unsigned int)__popcll(b & lmask_lt);
            ab[k] = __ballot(fl && ((rank & 15u) == (unsigned)wid));
            cum += (unsigned int)__popcll(b);
        }
    }
}

// ---------- ball query: up-to-64 nearest in-radius (one wave / centroid) ----------

__global__ __launch_bounds__(256) void ballq_kernel(
        const float* __restrict__ pos,
        const float4* __restrict__ pq,
        const int* __restrict__ cstart, const int* __restrict__ sel,
        int* __restrict__ nbr, int* __restrict__ ncnt) {
    __shared__ float s_d2[4][CAP];
    __shared__ int   s_o[4][CAP];
    __shared__ int   s_cnt[4];

    const int wid  = threadIdx.x >> 6;
    const int lane = threadIdx.x & 63;
    const int m = blockIdx.x * 4 + wid;

    if (lane == 0) s_cnt[wid] = 0;
    __syncthreads();

    int sidx = sel[m];
    float cx = pos[3*sidx], cy = pos[3*sidx+1], cz = pos[3*sidx+2];
    int ix = clamp8((int)(cx * 8.0f));
    int iy = clamp8((int)(cy * 8.0f));
    int iz = clamp8((int)(cz * 8.0f));
    const float r2 = (float)(0.08 * 0.08);

    for (int dz = -1; dz <= 1; ++dz) {
        int z = iz + dz; if (z < 0 || z > 7) continue;
        for (int dy = -1; dy <= 1; ++dy) {
            int y = iy + dy; if (y < 0 || y > 7) continue;
            for (int dx = -1; dx <= 1; ++dx) {
                int xq = ix + dx; if (xq < 0 || xq > 7) continue;
                int c = (z * 8 + y) * 8 + xq;
                int cs = cstart[c], ce = cstart[c + 1];
                for (int j = cs + lane; j < ce; j += 64) {
                    float4 q = pq[j];
                    float d2 = d2_exact(cx, cy, cz, q.x, q.y, q.z);
                    if (d2 <= r2) {
                        int slot = atomicAdd(&s_cnt[wid], 1);
                        if (slot < CAP) { s_d2[wid][slot] = d2; s_o[wid][slot] = __float_as_int(q.w); }
                    }
                }
            }
        }
    }
    __syncthreads();

    int cnt = s_cnt[wid];
    if (cnt > CAP) cnt = CAP;
    if (cnt <= K_NBR) {
        if (lane < cnt) nbr[m * K_NBR + lane] = s_o[wid][lane];
        if (lane == 0) ncnt[m] = cnt;
    } else {
        // exact (d2, orig-index) lexicographic rank -> keep 64 nearest (matches top_k)
        for (int i = lane; i < cnt; i += 64) {
            float d2 = s_d2[wid][i];
            int   o  = s_o[wid][i];
            int rank = 0;
            for (int j = 0; j < cnt; ++j) {
                float dj = s_d2[wid][j];
                int   oj = s_o[wid][j];
                rank += (dj < d2 || (dj == d2 && oj < o)) ? 1 : 0;
            }
            if (rank < K_NBR) nbr[m * K_NBR + rank] = o;
        }
        if (lane == 0) ncnt[m] = K_NBR;
    }
}

// ---------- PointConv MLP + masked max-pool (fp32, one block / centroid) ----------

__global__ __launch_bounds__(256) void mlp_kernel(
        const float* __restrict__ x, const float* __restrict__ pos,
        const float* __restrict__ W1, const float* __restrict__ b1,
        const float* __restrict__ W2, const float* __restrict__ b2,
        const int* __restrict__ sel, const int* __restrict__ nbr,
        const int* __restrict__ ncnt, float* __restrict__ out) {
    __shared__ __align__(16) float feat[64][68];   // 67 used + pad
    __shared__ __align__(16) float h[64][H_MID];
    __shared__ float part[2][H_MID];

    const int m = blockIdx.x;
    const int tid = threadIdx.x;
    const int cnt = ncnt[m];
    const int s = sel[m];
    float cx = pos[3*s], cy = pos[3*s+1], cz = pos[3*s+2];

    for (int i = tid; i < 64 * 68; i += 256) ((float*)feat)[i] = 0.0f;
    __syncthreads();

    for (int i = tid; i < cnt * F_IN; i += 256) {
        int k = i >> 6, f = i & 63;
        int j = nbr[m * K_NBR + k];
        feat[k][f] = x[(size_t)j * F_IN + f];
    }
    if (tid < 64 && tid < cnt) {
        int j = nbr[m * K_NBR + tid];
        feat[tid][64] = pos[3*j]     - cx;
        feat[tid][65] = pos[3*j + 1] - cy;
        feat[tid][66] = pos[3*j + 2] - cz;
    }
    __syncthreads();

    const int c = tid & 127;
    const int half = tid >> 7;

    for (int k = half; k < 64; k += 2) {
        float acc = b1[c];
        const float4* fr = (const float4*)&feat[k][0];
#pragma unroll
        for (int f4 = 0; f4 < 16; ++f4) {
            float4 fv = fr[f4];
            int fb = f4 * 4;
            acc = fmaf(fv.x, W1[(fb    ) * H_MID + c], acc);
            acc = fmaf(fv.y, W1[(fb + 1) * H_MID + c], acc);
            acc = fmaf(fv.z, W1[(fb + 2) * H_MID + c], acc);
            acc = fmaf(fv.w, W1[(fb + 3) * H_MID + c], acc);
        }
        acc = fmaf(feat[k][64], W1[64 * H_MID + c], acc);
        acc = fmaf(feat[k][65], W1[65 * H_MID + c], acc);
        acc = fmaf(feat[k][66], W1[66 * H_MID + c], acc);
        h[k][c] = fmaxf(acc, 0.0f);
    }
    __syncthreads();

    float best = -INFINITY;
    for (int k = half; k < cnt; k += 2) {
        float acc = 0.0f;
        const float4* hr = (const float4*)&h[k][0];
#pragma unroll
        for (int q = 0; q < 32; ++q) {
            float4 hv = hr[q];
            int hb = q * 4;
            acc = fmaf(hv.x, W2[(hb    ) * C_OUT + c], acc);
            acc = fmaf(hv.y, W2[(hb + 1) * C_OUT + c], acc);
            acc = fmaf(hv.z, W2[(hb + 2) * C_OUT + c], acc);
            acc = fmaf(hv.w, W2[(hb + 3) * C_OUT + c], acc);
        }
        best = fmaxf(best, acc);
    }
    part[half][c] = best;
    __syncthreads();
    if (tid < 128) {
        out[(size_t)m * C_OUT + tid] = fmaxf(part[0][tid], part[1][tid]) + b2[tid];
    }
}

// ---------- outputs 2 & 3 ----------

__global__ void tail_kernel(const float* __restrict__ pos, const int* __restrict__ sel,
                            float* __restrict__ out_selpos, float* __restrict__ out_batch) {
    int i = blockIdx.x * blockDim.x + threadIdx.x;
    if (i < M_SEL) {
        int s = sel[i];
        out_selpos[3*i]     = pos[3*s];
        out_selpos[3*i + 1] = pos[3*s + 1];
        out_selpos[3*i + 2] = pos[3*s + 2];
        out_batch[i] = 0.0f;
    }
}

// ---------- launch ----------

extern "C" void kernel_launch(void* const* d_in, const int* in_sizes, int n_in,
                              void* d_out, int out_size, void* d_ws, size_t ws_size,
                              hipStream_t stream) {
    const float* x   = (const float*)d_in[0];
    const float* pos = (const float*)d_in[1];
    // d_in[2] = batch (int64, all zeros) — unused
    const float* W1 = (const float*)d_in[3];
    const float* b1 = (const float*)d_in[4];
    const float* W2 = (const float*)d_in[5];
    const float* b2 = (const float*)d_in[6];

    float* out        = (float*)d_out;
    float* out_selpos = out + (size_t)M_SEL * C_OUT;
    float* out_batch  = out_selpos + (size_t)M_SEL * 3;

    char* ws = (char*)d_ws;
    size_t off = 0;
    auto alloc = [&](size_t bytes) -> void* {
        void* p = ws + off;
        off = (off + bytes + 255) & ~(size_t)255;
        return p;
    };
    int*    cnt    = (int*)alloc(NCELL * 4);
    int*    cstart = (int*)alloc((NCELL + 1) * 4);
    int*    cfill  = (int*)alloc(NCELL * 4);
    float4* pq     = (float4*)alloc((size_t)N_PTS * 16);
    int*    sel    = (int*)alloc(M_SEL * 4);
    int*    nbr    = (int*)alloc((size_t)M_SEL * K_NBR * 4);
    int*    ncnt   = (int*)alloc(M_SEL * 4);
    (void)ws_size; (void)in_sizes; (void)n_in; (void)out_size;

    (void)hipMemsetAsync(cnt, 0, NCELL * 4, stream);
    bin_count_kernel<<<N_PTS / 256, 256, 0, stream>>>(pos, cnt);
    scan_kernel<<<1, NCELL, 0, stream>>>(cnt, cstart, cfill);
    scatter_kernel<<<N_PTS / 256, 256, 0, stream>>>(pos, cfill, pq);
    fps_kernel<<<1, 1024, 0, stream>>>(pq, cstart, pos, sel);
    ballq_kernel<<<M_SEL / 4, 256, 0, stream>>>(pos, pq, cstart, sel, nbr, ncnt);
    mlp_kernel<<<M_SEL, 256, 0, stream>>>(x, pos, W1, b1, W2, b2, sel, nbr, ncnt, out);
    tail_kernel<<<(M_SEL + 255) / 256, 256, 0, stream>>>(pos, sel, out_selpos, out_batch);
}

// Round 5
// 17252.838 us; speedup vs baseline: 3.0543x; 3.0543x over previous
//
#include <hip/hip_runtime.h>
#include <math.h>

#define N_PTS 32768
#define M_SEL 8192
#define K_NBR 64
#define F_IN  64
#define H_MID 128
#define C_OUT 128
#define NCELL 512   // 8x8x8 grid
#define CAP   192   // per-centroid candidate cap
#define NW    4     // waves in fps block
#define NT    (NW * 64)

// ---------- helpers ----------

__device__ __forceinline__ int clamp8(int v) { return v < 0 ? 0 : (v > 7 ? 7 : v); }

__device__ __forceinline__ int cell_of(float px, float py, float pz) {
    int ix = clamp8((int)(px * 8.0f));
    int iy = clamp8((int)(py * 8.0f));
    int iz = clamp8((int)(pz * 8.0f));
    return (iz * 8 + iy) * 8 + ix;
}

// Bit-exact replica of numpy: ((dx*dx + dy*dy) + dz*dz), rn, no fma.
__device__ __forceinline__ float d2_exact(float ax, float ay, float az,
                                          float bx, float by, float bz) {
#pragma clang fp contract(off)
    float dx = ax - bx, dy = ay - by, dz = az - bz;
    return (dx * dx + dy * dy) + dz * dz;
}

__device__ __forceinline__ unsigned long long umax64(unsigned long long a,
                                                     unsigned long long b) {
    return a > b ? a : b;
}

// ---------- binning ----------

__global__ void bin_count_kernel(const float* __restrict__ pos, int* __restrict__ cnt) {
    int i = blockIdx.x * blockDim.x + threadIdx.x;
    if (i < N_PTS) {
        atomicAdd(&cnt[cell_of(pos[3*i], pos[3*i+1], pos[3*i+2])], 1);
    }
}

__global__ void scan_kernel(const int* __restrict__ cnt, int* __restrict__ start,
                            int* __restrict__ fill) {
    __shared__ int s[NCELL];
    int t = threadIdx.x;
    int v = cnt[t];
    s[t] = v;
    __syncthreads();
    for (int off = 1; off < NCELL; off <<= 1) {
        int add = (t >= off) ? s[t - off] : 0;
        __syncthreads();
        s[t] += add;
        __syncthreads();
    }
    int ex = s[t] - v;           // exclusive scan
    start[t] = ex;
    fill[t]  = ex;
    if (t == NCELL - 1) start[NCELL] = s[t];
}

// pq[slot] = (x, y, z, orig_index_as_float_bits) — one dwordx4 per point
__global__ void scatter_kernel(const float* __restrict__ pos, int* __restrict__ fill,
                               float4* __restrict__ pq) {
    int i = blockIdx.x * blockDim.x + threadIdx.x;
    if (i < N_PTS) {
        float px = pos[3*i], py = pos[3*i+1], pz = pos[3*i+2];
        int c = cell_of(px, py, pz);
        int slot = atomicAdd(&fill[c], 1);
        pq[slot] = make_float4(px, py, pz, __int_as_float(i));
    }
}

// ---------- FPS ----------
// 256 threads (4 waves) on one CU. mind[] LDS-resident. Per-cell max = 4 u64
// sub-slots maintained by ds_max_u64 (lane>>4), consolidated into s_best after
// each update phase. Global argmax replicated per wave via an 8-slot LDS
// atomic tree (no shuffles, no extra barrier). 2 barriers/iteration.

__global__ __launch_bounds__(NT) void fps_kernel(
        const float4* __restrict__ pq, const int* __restrict__ cstart,
        const float* __restrict__ pos, int* __restrict__ sel) {
    __shared__ float s_mind[N_PTS];                       // 128 KB
    __shared__ unsigned long long s_sub[NCELL][4];        // 16 KB (uninit ok)
    __shared__ unsigned long long s_best[NCELL];          // 4 KB
    __shared__ unsigned long long s_redw[NW][8];          // 256 B
    __shared__ int s_cs[NCELL + 1];

    const int tid  = threadIdx.x;
    const int lane = tid & 63;
    const int wid  = tid >> 6;
    const unsigned long long lmask_lt = (1ULL << lane) - 1ULL;

    for (int i = tid; i < N_PTS; i += NT) s_mind[i] = INFINITY;
    for (int i = tid; i < NCELL + 1; i += NT) s_cs[i] = cstart[i];
    for (int c = tid; c < NCELL; c += NT)
        s_best[c] = (cstart[c + 1] > cstart[c])
                    ? ((0x7F800000ULL << 32) | 0xFFFFFFFFULL) : 0ULL;
    if (lane < 8) s_redw[wid][lane] = 0ULL;
    if (tid == 0) sel[0] = 0;
    __syncthreads();

    // per-lane cell geometry (cells lane + 64k)
    float lox[8], loy[8], loz[8];
    #pragma unroll
    for (int k = 0; k < 8; ++k) {
        const int c = lane + (k << 6);
        lox[k] = (float)(c & 7)        * 0.125f;
        loy[k] = (float)((c >> 3) & 7) * 0.125f;
        loz[k] = (float)(c >> 6)       * 0.125f;
    }

    unsigned long long vb[8];     // current per-cell best (replicated view)
    unsigned long long fm[8];     // full flag masks (identical in all waves)
    unsigned long long ab[8];     // this wave's assigned subset
    float px = pos[0], py = pos[1], pz = pos[2];

    #pragma unroll
    for (int k = 0; k < 8; ++k) vb[k] = s_best[lane + (k << 6)];

    auto flag_assign = [&]() {
        unsigned int cum = 0;
        #pragma unroll
        for (int k = 0; k < 8; ++k) {
            const float cm = __uint_as_float((unsigned int)(vb[k] >> 32));
            float dx = fmaxf(fmaxf(lox[k] - px, px - (lox[k] + 0.125f)), 0.0f);
            float dy = fmaxf(fmaxf(loy[k] - py, py - (loy[k] + 0.125f)), 0.0f);
            float dz = fmaxf(fmaxf(loz[k] - pz, pz - (loz[k] + 0.125f)), 0.0f);
            float lb2 = dx * dx + dy * dy + dz * dz;
            bool fl = (lb2 * 0.999f < cm);               // conservative skip bound
            unsigned long long b = __ballot(fl);
            fm[k] = b;
            unsigned int rank = cum + (unsigned int)__popcll(b & lmask_lt);
            ab[k] = __ballot(fl && ((rank & (NW - 1)) == (unsigned)wid));
            cum += (unsigned int)__popcll(b);
        }
    };
    flag_assign();

    for (int m = 1; m < M_SEL; ++m) {
        // ---- B: update this wave's assigned cells ----
        if (lane < 8) s_redw[wid][lane] = 0ULL;          // reset own reduce slots
        #pragma unroll
        for (int k = 0; k < 8; ++k) {
            unsigned long long mask = ab[k];
            while (mask) {
                const int bit = __ffsll((long long)mask) - 1;
                mask &= mask - 1;
                const int c = bit + (k << 6);
                if (lane < 4) s_sub[c][lane] = 0ULL;     // in-order before atomics
                const int cs = s_cs[c], ce = s_cs[c + 1];
                for (int j = cs + lane; j < ce; j += 64) {
                    const float4 q  = pq[j];
                    const float d2  = d2_exact(q.x, q.y, q.z, px, py, pz);
                    const float old = s_mind[j];
                    const float nv  = d2 < old ? d2 : old;
                    s_mind[j] = nv;
                    const unsigned long long pk =
                        ((unsigned long long)__float_as_uint(nv) << 32)
                        | (unsigned long long)(~(unsigned int)__float_as_int(q.w));
                    atomicMax(&s_sub[c][lane >> 4], pk);
                }
            }
        }
        __syncthreads();

        // ---- D: consolidate flagged cells, replicated argmax over 512 ----
        unsigned long long best = 0ULL;
        #pragma unroll
        for (int k = 0; k < 8; ++k) {
            const int c = lane + (k << 6);
            unsigned long long v;
            if ((fm[k] >> lane) & 1ULL) {
                const unsigned long long v0 = s_sub[c][0], v1 = s_sub[c][1];
                const unsigned long long v2 = s_sub[c][2], v3 = s_sub[c][3];
                v = umax64(umax64(v0, v1), umax64(v2, v3));
                if (wid == 0) s_best[c] = v;             // persist for later iters
            } else {
                v = s_best[c];
            }
            vb[k] = v;
            best = umax64(best, v);
        }
        atomicMax(&s_redw[wid][lane & 7], best);         // intra-wave tree, in-order
        #pragma unroll
        for (int i = 0; i < 8; ++i) best = umax64(best, s_redw[wid][i]);

        const unsigned int orig = ~(unsigned int)best;
        if (tid == 0) sel[m] = (int)orig;
        px = pos[3 * orig]; py = pos[3 * orig + 1]; pz = pos[3 * orig + 2];

        // ---- F: flags + assignment for next iteration (register-only) ----
        flag_assign();
        __syncthreads();     // D/F reads done before next B's writes
    }
}

// ---------- ball query: up-to-64 nearest in-radius (one wave / centroid) ----------

__global__ __launch_bounds__(256) void ballq_kernel(
        const float* __restrict__ pos,
        const float4* __restrict__ pq,
        const int* __restrict__ cstart, const int* __restrict__ sel,
        int* __restrict__ nbr, int* __restrict__ ncnt) {
    __shared__ float s_d2[4][CAP];
    __shared__ int   s_o[4][CAP];
    __shared__ int   s_cnt[4];

    const int wid  = threadIdx.x >> 6;
    const int lane = threadIdx.x & 63;
    const int m = blockIdx.x * 4 + wid;

    if (lane == 0) s_cnt[wid] = 0;
    __syncthreads();

    int sidx = sel[m];
    float cx = pos[3*sidx], cy = pos[3*sidx+1], cz = pos[3*sidx+2];
    int ix = clamp8((int)(cx * 8.0f));
    int iy = clamp8((int)(cy * 8.0f));
    int iz = clamp8((int)(cz * 8.0f));
    const float r2 = (float)(0.08 * 0.08);

    for (int dz = -1; dz <= 1; ++dz) {
        int z = iz + dz; if (z < 0 || z > 7) continue;
        for (int dy = -1; dy <= 1; ++dy) {
            int y = iy + dy; if (y < 0 || y > 7) continue;
            for (int dx = -1; dx <= 1; ++dx) {
                int xq = ix + dx; if (xq < 0 || xq > 7) continue;
                int c = (z * 8 + y) * 8 + xq;
                int cs = cstart[c], ce = cstart[c + 1];
                for (int j = cs + lane; j < ce; j += 64) {
                    float4 q = pq[j];
                    float d2 = d2_exact(cx, cy, cz, q.x, q.y, q.z);
                    if (d2 <= r2) {
                        int slot = atomicAdd(&s_cnt[wid], 1);
                        if (slot < CAP) { s_d2[wid][slot] = d2; s_o[wid][slot] = __float_as_int(q.w); }
                    }
                }
            }
        }
    }
    __syncthreads();

    int cnt = s_cnt[wid];
    if (cnt > CAP) cnt = CAP;
    if (cnt <= K_NBR) {
        if (lane < cnt) nbr[m * K_NBR + lane] = s_o[wid][lane];
        if (lane == 0) ncnt[m] = cnt;
    } else {
        // exact (d2, orig-index) lexicographic rank -> keep 64 nearest (matches top_k)
        for (int i = lane; i < cnt; i += 64) {
            float d2 = s_d2[wid][i];
            int   o  = s_o[wid][i];
            int rank = 0;
            for (int j = 0; j < cnt; ++j) {
                float dj = s_d2[wid][j];
                int   oj = s_o[wid][j];
                rank += (dj < d2 || (dj == d2 && oj < o)) ? 1 : 0;
            }
            if (rank < K_NBR) nbr[m * K_NBR + rank] = o;
        }
        if (lane == 0) ncnt[m] = K_NBR;
    }
}

// ---------- PointConv MLP + masked max-pool (fp32, one block / centroid) ----------

__global__ __launch_bounds__(256) void mlp_kernel(
        const float* __restrict__ x, const float* __restrict__ pos,
        const float* __restrict__ W1, const float* __restrict__ b1,
        const float* __restrict__ W2, const float* __restrict__ b2,
        const int* __restrict__ sel, const int* __restrict__ nbr,
        const int* __restrict__ ncnt, float* __restrict__ out) {
    __shared__ __align__(16) float feat[64][68];   // 67 used + pad
    __shared__ __align__(16) float h[64][H_MID];
    __shared__ float part[2][H_MID];

    const int m = blockIdx.x;
    const int tid = threadIdx.x;
    const int cnt = ncnt[m];
    const int s = sel[m];
    float cx = pos[3*s], cy = pos[3*s+1], cz = pos[3*s+2];

    for (int i = tid; i < 64 * 68; i += 256) ((float*)feat)[i] = 0.0f;
    __syncthreads();

    for (int i = tid; i < cnt * F_IN; i += 256) {
        int k = i >> 6, f = i & 63;
        int j = nbr[m * K_NBR + k];
        feat[k][f] = x[(size_t)j * F_IN + f];
    }
    if (tid < 64 && tid < cnt) {
        int j = nbr[m * K_NBR + tid];
        feat[tid][64] = pos[3*j]     - cx;
        feat[tid][65] = pos[3*j + 1] - cy;
        feat[tid][66] = pos[3*j + 2] - cz;
    }
    __syncthreads();

    const int c = tid & 127;
    const int half = tid >> 7;

    for (int k = half; k < 64; k += 2) {
        float acc = b1[c];
        const float4* fr = (const float4*)&feat[k][0];
#pragma unroll
        for (int f4 = 0; f4 < 16; ++f4) {
            float4 fv = fr[f4];
            int fb = f4 * 4;
            acc = fmaf(fv.x, W1[(fb    ) * H_MID + c], acc);
            acc = fmaf(fv.y, W1[(fb + 1) * H_MID + c], acc);
            acc = fmaf(fv.z, W1[(fb + 2) * H_MID + c], acc);
            acc = fmaf(fv.w, W1[(fb + 3) * H_MID + c], acc);
        }
        acc = fmaf(feat[k][64], W1[64 * H_MID + c], acc);
        acc = fmaf(feat[k][65], W1[65 * H_MID + c], acc);
        acc = fmaf(feat[k][66], W1[66 * H_MID + c], acc);
        h[k][c] = fmaxf(acc, 0.0f);
    }
    __syncthreads();

    float best = -INFINITY;
    for (int k = half; k < cnt; k += 2) {
        float acc = 0.0f;
        const float4* hr = (const float4*)&h[k][0];
#pragma unroll
        for (int q = 0; q < 32; ++q) {
            float4 hv = hr[q];
            int hb = q * 4;
            acc = fmaf(hv.x, W2[(hb    ) * C_OUT + c], acc);
            acc = fmaf(hv.y, W2[(hb + 1) * C_OUT + c], acc);
            acc = fmaf(hv.z, W2[(hb + 2) * C_OUT + c], acc);
            acc = fmaf(hv.w, W2[(hb + 3) * C_OUT + c], acc);
        }
        best = fmaxf(best, acc);
    }
    part[half][c] = best;
    __syncthreads();
    if (tid < 128) {
        out[(size_t)m * C_OUT + tid] = fmaxf(part[0][tid], part[1][tid]) + b2[tid];
    }
}

// ---------- outputs 2 & 3 ----------

__global__ void tail_kernel(const float* __restrict__ pos, const int* __restrict__ sel,
                            float* __restrict__ out_selpos, float* __restrict__ out_batch) {
    int i = blockIdx.x * blockDim.x + threadIdx.x;
    if (i < M_SEL) {
        int s = sel[i];
        out_selpos[3*i]     = pos[3*s];
        out_selpos[3*i + 1] = pos[3*s + 1];
        out_selpos[3*i + 2] = pos[3*s + 2];
        out_batch[i] = 0.0f;
    }
}

// ---------- launch ----------

extern "C" void kernel_launch(void* const* d_in, const int* in_sizes, int n_in,
                              void* d_out, int out_size, void* d_ws, size_t ws_size,
                              hipStream_t stream) {
    const float* x   = (const float*)d_in[0];
    const float* pos = (const float*)d_in[1];
    // d_in[2] = batch (int64, all zeros) — unused
    const float* W1 = (const float*)d_in[3];
    const float* b1 = (const float*)d_in[4];
    const float* W2 = (const float*)d_in[5];
    const float* b2 = (const float*)d_in[6];

    float* out        = (float*)d_out;
    float* out_selpos = out + (size_t)M_SEL * C_OUT;
    float* out_batch  = out_selpos + (size_t)M_SEL * 3;

    char* ws = (char*)d_ws;
    size_t off = 0;
    auto alloc = [&](size_t bytes) -> void* {
        void* p = ws + off;
        off = (off + bytes + 255) & ~(size_t)255;
        return p;
    };
    int*    cnt    = (int*)alloc(NCELL * 4);
    int*    cstart = (int*)alloc((NCELL + 1) * 4);
    int*    cfill  = (int*)alloc(NCELL * 4);
    float4* pq     = (float4*)alloc((size_t)N_PTS * 16);
    int*    sel    = (int*)alloc(M_SEL * 4);
    int*    nbr    = (int*)alloc((size_t)M_SEL * K_NBR * 4);
    int*    ncnt   = (int*)alloc(M_SEL * 4);
    (void)ws_size; (void)in_sizes; (void)n_in; (void)out_size;

    (void)hipMemsetAsync(cnt, 0, NCELL * 4, stream);
    bin_count_kernel<<<N_PTS / 256, 256, 0, stream>>>(pos, cnt);
    scan_kernel<<<1, NCELL, 0, stream>>>(cnt, cstart, cfill);
    scatter_kernel<<<N_PTS / 256, 256, 0, stream>>>(pos, cfill, pq);
    fps_kernel<<<1, NT, 0, stream>>>(pq, cstart, pos, sel);
    ballq_kernel<<<M_SEL / 4, 256, 0, stream>>>(pos, pq, cstart, sel, nbr, ncnt);
    mlp_kernel<<<M_SEL, 256, 0, stream>>>(x, pos, W1, b1, W2, b2, sel, nbr, ncnt, out);
    tail_kernel<<<(M_SEL + 255) / 256, 256, 0, stream>>>(pos, sel, out_selpos, out_batch);
}